// Round 8
// baseline (9023.298 us; speedup 1.0000x reference)
//
#include <hip/hip_runtime.h>

// Handwriting synthesis RNN — persistent fused kernel, R8: MERGED ROLES.
// 256 blocks (4 bgroups x 64 peers), lockstep via one 64-flag ballot poll per
// step. Each block: 32 gates1 cols + 32 gates2 cols + redundant attention +
// one 16-col MDN window (block 63: pi + softmax). Exactly ONE poll + ONE ring
// burst + ONE drain + ONE flag per step (R7 lesson: MALL RTs are the cost,
// compute is free). X tile double-buffers h1 by parity so MDN reads h1[t-2]
// from LDS. Weights in VGPRs (1 blk/CU => 512-VGPR budget; LDS ~90KB forces
// even 1/CU placement).

typedef unsigned short u16;
typedef unsigned int   u32;
typedef unsigned long long u64;
typedef u16   u16x8  __attribute__((ext_vector_type(8)));
typedef __bf16 bf16x8 __attribute__((ext_vector_type(8)));
typedef float f32x4  __attribute__((ext_vector_type(4)));

#define DEV static __device__ __forceinline__

#define BT   64
#define TT   800
#define UU   64
#define HH   512
#define SENT 60
#define NG   2048
#define MOUT 121
#define K1P 576
#define K2P 1088
#define KSW 512
#define MDC 144          // padded MDN cols

#define NBG 4
#define BPG 64
#define NBLK (NBG*BPG)   // 256
#define RD   4
#define XS   1672        // X row stride (u16): 1664 cols + 8 pad

// workspace layout (bytes)
#define OFF_BAR 0
#define OFF_H1  4096
#define OFF_H2  (OFF_H1 + RD*BT*HH*2)
#define OFF_CM  (OFF_H2 + RD*BT*HH*2)
#define OFF_W1  (OFF_CM + 32768)
#define OFF_W2  (OFF_W1 + NG*K1P*2)
#define OFF_WSW (OFF_W2 + NG*K2P*2)
#define OFF_WMD (OFF_WSW + 32*KSW*2)
#define OFF_B1  (OFF_WMD + MDC*1024*2)
#define OFF_B2  (OFF_B1 + NG*4)
#define OFF_BSW (OFF_B2 + NG*4)
#define OFF_BMD (OFF_BSW + 256)
#define WS_NEED (OFF_BMD + 1024)
#define ZERO_BYTES OFF_CM

// output offsets (floats)
#define OW_EOS 0
#define OW_W   (BT*TT)
#define OW_MU1 (OW_W   + BT*TT*20)
#define OW_MU2 (OW_MU1 + BT*TT*20)
#define OW_S1  (OW_MU2 + BT*TT*20)
#define OW_S2  (OW_S1  + BT*TT*20)
#define OW_RHO (OW_S2  + BT*TT*20)

DEV u16 f2bf(float f){
  u32 u = __builtin_bit_cast(u32, f);
  u = (u + 0x7FFFu + ((u >> 16) & 1u)) >> 16;
  return (u16)u;
}
DEV bf16x8 ld8(const u16* p){ return __builtin_bit_cast(bf16x8, *(const u16x8*)p); }
DEV f32x4 mfma16(bf16x8 a, bf16x8 b, f32x4 c){
  return __builtin_amdgcn_mfma_f32_16x16x32_bf16(a, b, c, 0, 0, 0);
}
DEV float sig_(float x){ return 1.f/(1.f + __expf(-x)); }
DEV float tanh_(float x){
  float ax = fabsf(x);
  float e  = __expf(-2.f*ax);
  float t2 = (1.f - e)/(1.f + e);
  return x < 0.f ? -t2 : t2;
}

// ---- device-scope (MALL-coherent) helpers ----
DEV void ld_tile8(const u16* p1, const u16* p2,
                  u16x8& a0,u16x8& a1,u16x8& a2,u16x8& a3,
                  u16x8& b0,u16x8& b1,u16x8& b2,u16x8& b3){
  asm volatile(
    "global_load_dwordx4 %0, %8, off sc0 sc1\n\t"
    "global_load_dwordx4 %1, %8, off offset:256 sc0 sc1\n\t"
    "global_load_dwordx4 %2, %8, off offset:512 sc0 sc1\n\t"
    "global_load_dwordx4 %3, %8, off offset:768 sc0 sc1\n\t"
    "global_load_dwordx4 %4, %9, off sc0 sc1\n\t"
    "global_load_dwordx4 %5, %9, off offset:256 sc0 sc1\n\t"
    "global_load_dwordx4 %6, %9, off offset:512 sc0 sc1\n\t"
    "global_load_dwordx4 %7, %9, off offset:768 sc0 sc1\n\t"
    "s_waitcnt vmcnt(0)"
    : "=&v"(a0),"=&v"(a1),"=&v"(a2),"=&v"(a3),
      "=&v"(b0),"=&v"(b1),"=&v"(b2),"=&v"(b3)
    : "v"(p1), "v"(p2) : "memory");
}
DEV void st_x4_sc(u16* p, u16x8 v){
  asm volatile("global_store_dwordx4 %0, %1, off sc0 sc1" :: "v"(p), "v"(v) : "memory");
}
DEV void st_dword_sc(u32* p, u32 v){
  asm volatile("global_store_dword %0, %1, off sc0 sc1" :: "v"(p), "v"(v) : "memory");
}
DEV void vmwait0(){ asm volatile("s_waitcnt vmcnt(0)" ::: "memory"); }
DEV u32 scld_u32(const u32* p){
  u32 v;
  asm volatile("global_load_dword %0, %1, off sc0 sc1\n\ts_waitcnt vmcnt(0)"
    : "=&v"(v) : "v"(p) : "memory");
  return v;
}
// wave0-only: lane L checks flags[L] >= thr (all 64 peers).
DEV void poll_flags(const u32* flags, int lane, int thr){
  const u32* p = flags + lane;
  for(;;){
    u32 v = scld_u32(p);
    if (__ballot((int)v >= thr) == ~0ull) return;
    __builtin_amdgcn_s_sleep(1);
  }
}

// ---------------- weight/bias/mask pre-pack ----------------
__global__ __launch_bounds__(256) void pack_kernel(
    const float* __restrict__ Wih1, const float* __restrict__ Whh1,
    const float* __restrict__ bih1, const float* __restrict__ bhh1,
    const float* __restrict__ Wih2, const float* __restrict__ Whh2,
    const float* __restrict__ bih2, const float* __restrict__ bhh2,
    const float* __restrict__ Wsw,  const float* __restrict__ bsw,
    const float* __restrict__ Wmdn, const float* __restrict__ bmdn,
    const float* __restrict__ onehots, char* __restrict__ ws)
{
  u16* Wp1  = (u16*)(ws + OFF_W1);
  u16* Wp2  = (u16*)(ws + OFF_W2);
  u16* Wswp = (u16*)(ws + OFF_WSW);
  u16* Wmdp = (u16*)(ws + OFF_WMD);
  float* b1p  = (float*)(ws + OFF_B1);
  float* b2p  = (float*)(ws + OFF_B2);
  float* bswp = (float*)(ws + OFF_BSW);
  float* bmdp = (float*)(ws + OFF_BMD);
  u64* cmask = (u64*)(ws + OFF_CM);

  const int SA = NG*K1P, SB = NG*K2P, SC = 32*KSW, SD = MDC*1024;
  const int SE = NG + NG + 32 + MDC, SF = BT*SENT;
  const int total = SA+SB+SC+SD+SE+SF;
  for (int i = blockIdx.x*blockDim.x + threadIdx.x; i < total; i += gridDim.x*blockDim.x){
    if (i < SA){
      // Wp1 col layout: [h1:512][w:60][strk:3][pad:1]
      const int n = i / K1P, k = i - n*K1P;
      const int r = (n&3)*HH + (n>>2);
      float f;
      if (k < 512)      f = Whh1[r*HH + k];
      else if (k < 572) f = Wih1[r*63 + 3 + (k-512)];   // w
      else if (k < 575) f = Wih1[r*63 + (k-572)];       // strk
      else              f = 0.f;
      Wp1[i] = f2bf(f);
    } else if (i < SA+SB){
      // Wp2 col layout: [h1:512][h2:512][w:60][strk:3][pad:1]
      const int j = i - SA;
      const int n = j / K2P, k = j - n*K2P;
      const int r = (n&3)*HH + (n>>2);
      float f;
      if (k < 512)       f = Wih2[r*575 + 3 + k];
      else if (k < 1024) f = Whh2[r*HH + (k-512)];
      else if (k < 1084) f = Wih2[r*575 + 515 + (k-1024)];
      else if (k < 1087) f = Wih2[r*575 + (k-1084)];
      else               f = 0.f;
      Wp2[j] = f2bf(f);
    } else if (i < SA+SB+SC){
      const int j = i - SA - SB;
      const int n = j >> 9, k = j & 511;
      Wswp[j] = f2bf(n < 30 ? Wsw[n*KSW + k] : 0.f);
    } else if (i < SA+SB+SC+SD){
      const int j = i - SA - SB - SC;
      const int n = j >> 10, k = j & 1023;
      float f = 0.f;
      if (n < MOUT) f = (k < 512) ? Wmdn[n*1536 + k]
                                  : (Wmdn[n*1536 + 512 + (k-512)] + Wmdn[n*1536 + 1024 + (k-512)]);
      Wmdp[j] = f2bf(f);
    } else if (i < SA+SB+SC+SD+SE){
      int j = i - SA - SB - SC - SD;
      if (j < NG){ const int r=(j&3)*HH+(j>>2); b1p[j] = bih1[r] + bhh1[r]; }
      else if ((j -= NG) < NG){ const int r=(j&3)*HH+(j>>2); b2p[j] = bih2[r] + bhh2[r]; }
      else if ((j -= NG) < 32){ bswp[j] = (j < 30) ? bsw[j] : 0.f; }
      else { j -= 32; bmdp[j] = (j < MOUT) ? bmdn[j] : 0.f; }
    } else {
      const int j = i - SA - SB - SC - SD - SE;
      const int b = j / SENT, c = j - b*SENT;
      const float* oh = onehots + b*UU*SENT + c;
      u64 m = 0;
#pragma unroll 1
      for (int u = 0; u < UU; ++u) if (oh[u*SENT] > 0.5f) m |= (1ull << u);
      cmask[j] = m;
    }
  }
}

// X col map: [h1A:512][h1B:512][h2:512][tail1:64][tail2:64]
//  tail1 (GEMM1, step t):   1536+[w:60][strk_t:3][pad:1]
//  tail2 (GEMM2, step t-1): 1600+[w:60][strk_{t-1}:3][pad:1]
struct SMEM {
  u16   X[16*XS];
  float pp[1024];          // attn partials [kh][16][32]
  float pp1[1088];         // gates1 partials [kh][16][34]
  float pp2[1088];
  float ppm[2176];         // mdn partials [kh(4)][16][34]
  float aa[160], bb[160], kk[160];
  float smv[1024];
  u64   cm[960];
  float c1[128], c2[128];
  u16   h1b[128], h2b[128];
  float bias1L[32], bias2L[32], bmdL[20];
};

__global__ __launch_bounds__(256, 1) void rnn_main(
    const float* __restrict__ strks, const float* __restrict__ sm,
    const float* __restrict__ wprev, char* __restrict__ ws,
    float* __restrict__ out)
{
  u32* bar   = (u32*)(ws + OFF_BAR);
  u16* h1pub = (u16*)(ws + OFF_H1);
  u16* h2pub = (u16*)(ws + OFF_H2);
  const u64* cmask = (const u64*)(ws + OFF_CM);
  const u16* Wp1  = (const u16*)(ws + OFF_W1);
  const u16* Wp2  = (const u16*)(ws + OFF_W2);
  const u16* Wswp = (const u16*)(ws + OFF_WSW);
  const u16* Wmdp = (const u16*)(ws + OFF_WMD);
  const float* b1p  = (const float*)(ws + OFF_B1);
  const float* b2p  = (const float*)(ws + OFF_B2);
  const float* bswp = (const float*)(ws + OFF_BSW);
  const float* bmdp = (const float*)(ws + OFF_BMD);

  __shared__ SMEM S;

  const int bid = blockIdx.x, tid = threadIdx.x;
  const int wave = tid >> 6, lane = tid & 63;
  const int quad = lane >> 4, l15 = lane & 15;
  const int sb = tid >> 4, sl = tid & 15;
  const int ct = wave & 1, kh = wave >> 1;

  const int bg = bid >> 6, s = bid & 63;
  const int bg16 = bg*16;
  u32* fl = bar + bg*64;
  const bool do_easy = (s <= 50);
  const bool do_pi   = (s == 63);

  // ---- weights -> VGPRs ----
  bf16x8 w1r[9];
  { const int n1 = s*32 + ct*16 + l15;
#pragma unroll
    for (int i = 0; i < 9; ++i) w1r[i] = ld8(Wp1 + n1*K1P + quad*8 + (kh*9 + i)*32);
  }
  bf16x8 w2r[17];
  { const int n2 = s*32 + ct*16 + l15;
#pragma unroll
    for (int i = 0; i < 17; ++i) w2r[i] = ld8(Wp2 + n2*K2P + quad*8 + (kh*17 + i)*32);
  }
  bf16x8 wfr[8];
  { const int nsw = ct*16 + l15;
#pragma unroll
    for (int j = 0; j < 8; ++j) wfr[j] = ld8(Wswp + nsw*KSW + quad*8 + (kh*8 + j)*32);
  }
  bf16x8 wmr[16];
  if (do_easy){
    const int nm = 20 + 2*s + l15;
#pragma unroll
    for (int j = 0; j < 8; ++j) wmr[j] = ld8(Wmdp + nm*1024 + quad*8 + (wave*8 + j)*32);
  } else if (do_pi){
    const int nm = ct*16 + l15;
#pragma unroll
    for (int j = 0; j < 16; ++j) wmr[j] = ld8(Wmdp + nm*1024 + quad*8 + (kh*16 + j)*32);
  }
  float bswa = 0.f, bswb = 0.f, bswk = 0.f;
  if (tid < 160){ const int j = tid % 10; bswa = bswp[j]; bswb = bswp[10+j]; bswk = bswp[20+j]; }

  // ---- LDS init ----
  if (tid < 128) S.c1[tid] = 0.f; else S.c2[tid-128] = 0.f;
  if (tid < 160) S.kk[tid] = 0.f;
  for (int i = tid; i < 1024; i += 256) S.smv[i] = sm[(bg16 + (i>>6))*UU + (i&63)];
  for (int i = tid; i < 960;  i += 256) S.cm[i]  = cmask[(bg16 + i/60)*SENT + i%60];
  if (tid < 32) S.bias1L[tid] = b1p[s*32 + tid];
  else if (tid < 64) S.bias2L[tid-32] = b2p[s*32 + (tid-32)];
  if (do_easy && tid < 2)  S.bmdL[tid] = bmdp[20 + 2*s + tid];
  if (do_pi   && tid < 20) S.bmdL[tid] = bmdp[tid];
  if (tid < 16){ S.X[tid*XS + 1599] = 0; S.X[tid*XS + 1663] = 0; }
  __syncthreads();

  for (int t = 0; t <= TT + 1; ++t){
    const int par = t & 1, prv = par ^ 1;
    const float svt = (sl < 3 && t < TT)            ? strks[((bg16 + sb)*TT + t    )*3 + sl] : 0.f;
    const float svp = (sl < 3 && t >= 1 && t <= TT) ? strks[((bg16 + sb)*TT + (t-1))*3 + sl] : 0.f;

    if (wave == 0) poll_flags(fl, lane, t);
    __syncthreads();

    { // ---- ring burst: h1[t-1] + h2[t-2] -> X ----
      const u16* ph1 = h1pub + ((t+RD-1)&(RD-1))*(BT*HH) + (bg16 + sb)*HH + sl*8;
      const u16* ph2 = h2pub + ((t+RD-2)&(RD-1))*(BT*HH) + (bg16 + sb)*HH + sl*8;
      u16x8 a0,a1,a2,a3,b0,b1,b2v,b3;
      ld_tile8(ph1, ph2, a0,a1,a2,a3, b0,b1,b2v,b3);
      u16x8* xr = (u16x8*)(S.X + sb*XS);
      const int h1x = par*64;
      xr[h1x + sl] = a0; xr[h1x + sl + 16] = a1; xr[h1x + sl + 32] = a2; xr[h1x + sl + 48] = a3;
      xr[128 + sl] = b0; xr[128 + sl + 16] = b1; xr[128 + sl + 32] = b2v; xr[128 + sl + 48] = b3;
      if (sl < 3){
        S.X[sb*XS + 1596 + sl] = f2bf(svt);
        S.X[sb*XS + 1660 + sl] = f2bf(svp);
      }
    }
    __syncthreads();

    // ---- attention: w[t-1] from h1[t-1] (cur region); kappa local ----
    if (t >= 1 && t <= TT){
      f32x4 acc = {0.f,0.f,0.f,0.f};
      const u16* ap = S.X + l15*XS + par*512 + kh*256 + quad*8;
#pragma unroll
      for (int j = 0; j < 8; ++j) acc = mfma16(ld8(ap + j*32), wfr[j], acc);
#pragma unroll
      for (int r = 0; r < 4; ++r)
        S.pp[kh*512 + (quad*4 + r)*32 + ct*16 + l15] = acc[r];
    }
    __syncthreads();
    if (t >= 1 && t <= TT && tid < 160){
      const int b = tid/10, j = tid - b*10;
      S.aa[tid] = __expf(S.pp[b*32 + j]      + S.pp[512 + b*32 + j]      + bswa);
      S.bb[tid] = __expf(S.pp[b*32 + 10 + j] + S.pp[512 + b*32 + 10 + j] + bswb);
      S.kk[tid] += __expf(S.pp[b*32 + 20 + j] + S.pp[512 + b*32 + 20 + j] + bswk);
    }
    __syncthreads();
    if (t >= 1 && t <= TT){
#pragma unroll
      for (int p4 = 0; p4 < 4; ++p4){
        const int i = tid + p4*256;
        const int b = i >> 6, c = i & 63;
        if (c < 60){
          u64 m = S.cm[b*60 + c];
          float acc = 0.f;
          while (m){
            const int u = __builtin_ctzll(m); m &= m - 1;
            const float uf = (float)u;
            float sv = 0.f;
#pragma unroll
            for (int j = 0; j < 10; ++j){
              float d = S.kk[b*10 + j] - uf;
              sv = fmaf(S.aa[b*10 + j], __expf(-S.bb[b*10 + j]*d*d), sv);
            }
            acc = fmaf(sv, S.smv[b*64 + u], acc);
          }
          const u16 wv = f2bf(acc);
          S.X[b*XS + 1536 + c] = wv;
          S.X[b*XS + 1600 + c] = wv;
        }
      }
    } else if (t == 0){
      for (int i = tid; i < 960; i += 256){
        const int b = i/60, c = i - b*60;
        const u16 wv = f2bf(wprev[(bg16 + b)*SENT + c]);
        S.X[b*XS + 1536 + c] = wv;
        S.X[b*XS + 1600 + c] = wv;
      }
    }
    __syncthreads();

    // ---- GEMM1 (LSTM1 step t) ----
    if (t < TT){
      f32x4 acc = {0.f,0.f,0.f,0.f};
      const u16* xrow = S.X + l15*XS + quad*8;
      const u16* xh1  = xrow + par*512;
#pragma unroll
      for (int i = 0; i < 9; ++i){
        const int ktg = kh*9 + i;
        const u16* p = (ktg < 16) ? (xh1 + 32*ktg) : (xrow + 1536 + 32*(ktg-16));
        acc = mfma16(ld8(p), w1r[i], acc);
      }
#pragma unroll
      for (int r = 0; r < 4; ++r)
        S.pp1[kh*544 + (quad*4 + r)*34 + ct*16 + l15] = acc[r];
    }
    // ---- GEMM2 (LSTM2 step t-1) ----
    if (t >= 1 && t <= TT){
      f32x4 acc = {0.f,0.f,0.f,0.f};
      const u16* xrow = S.X + l15*XS + quad*8;
      const u16* xh1  = xrow + par*512;
#pragma unroll
      for (int i = 0; i < 17; ++i){
        const int ktg = kh*17 + i;
        const u16* p = (ktg < 16) ? (xh1 + 32*ktg)
                     : (ktg < 32) ? (xrow + 1024 + 32*(ktg-16))
                                  : (xrow + 1600 + 32*(ktg-32));
        acc = mfma16(ld8(p), w2r[i], acc);
      }
#pragma unroll
      for (int r = 0; r < 4; ++r)
        S.pp2[kh*544 + (quad*4 + r)*34 + ct*16 + l15] = acc[r];
    }
    // ---- MDN (step t-2): A = [h1prev | h2] ----
    if (t >= 2 && do_easy){
      f32x4 acc = {0.f,0.f,0.f,0.f};
      const u16* base = S.X + l15*XS + quad*8 +
                        (wave < 2 ? prv*512 + wave*256 : 1024 + (wave-2)*256);
#pragma unroll
      for (int j = 0; j < 8; ++j) acc = mfma16(ld8(base + j*32), wmr[j], acc);
#pragma unroll
      for (int r = 0; r < 4; ++r)
        S.ppm[wave*544 + (quad*4 + r)*34 + l15] = acc[r];
    }
    if (t >= 2 && do_pi){
      f32x4 acc = {0.f,0.f,0.f,0.f};
      const u16* xrow = S.X + l15*XS + quad*8;
#pragma unroll
      for (int j = 0; j < 16; ++j){
        const int ktg = kh*16 + j;
        const u16* p = (ktg < 16) ? (xrow + prv*512 + 32*ktg) : (xrow + 1024 + 32*(ktg-16));
        acc = mfma16(ld8(p), wmr[j], acc);
      }
#pragma unroll
      for (int r = 0; r < 4; ++r)
        S.ppm[kh*544 + (quad*4 + r)*34 + ct*16 + l15] = acc[r];
    }
    __syncthreads();

    // ---- pointwise ----
    if (t < TT && tid < 128){
      const int b = tid >> 3, hd = tid & 7;
      const float* p0 = S.pp1 + b*34 + hd*4;
      const float* p1 = S.pp1 + 544 + b*34 + hd*4;
      const float* bl = S.bias1L + hd*4;
      const float vi = p0[0]+p1[0]+bl[0], vf = p0[1]+p1[1]+bl[1];
      const float vg = p0[2]+p1[2]+bl[2], vo = p0[3]+p1[3]+bl[3];
      const float cn = sig_(vf)*S.c1[tid] + sig_(vi)*tanh_(vg);
      S.c1[tid] = cn;
      S.h1b[b*8 + hd] = f2bf(sig_(vo)*tanh_(cn));
    }
    if (t >= 1 && t <= TT && tid >= 128){
      const int q = tid - 128, b = q >> 3, hd = q & 7;
      const float* p0 = S.pp2 + b*34 + hd*4;
      const float* p1 = S.pp2 + 544 + b*34 + hd*4;
      const float* bl = S.bias2L + hd*4;
      const float vi = p0[0]+p1[0]+bl[0], vf = p0[1]+p1[1]+bl[1];
      const float vg = p0[2]+p1[2]+bl[2], vo = p0[3]+p1[3]+bl[3];
      const float cn = sig_(vf)*S.c2[q] + sig_(vi)*tanh_(vg);
      S.c2[q] = cn;
      S.h2b[b*8 + hd] = f2bf(sig_(vo)*tanh_(cn));
    }
    if (t >= 2 && do_easy && tid < 32){
      const int b = tid >> 1, j = tid & 1;
      const int col = 20 + 2*s + j;
      if (col <= 120){
        const float v = S.ppm[b*34 + j] + S.ppm[544 + b*34 + j] +
                        S.ppm[1088 + b*34 + j] + S.ppm[1632 + b*34 + j] + S.bmdL[j];
        const int bt = (bg16 + b)*TT + (t - 2);
        if (col < 40)       out[OW_MU1 + bt*20 + (col-20)]  = v;
        else if (col < 60)  out[OW_MU2 + bt*20 + (col-40)]  = v;
        else if (col < 80)  out[OW_S1  + bt*20 + (col-60)]  = __expf(v);
        else if (col < 100) out[OW_S2  + bt*20 + (col-80)]  = __expf(v);
        else if (col < 120) out[OW_RHO + bt*20 + (col-100)] = tanh_(v);
        else                out[OW_EOS + bt]                = sig_(v);
      }
    }
    if (t >= 2 && do_pi && tid < 16){
      const int b = tid;
      const int bt = (bg16 + b)*TT + (t - 2);
      float vv[20], mx = -1e30f;
#pragma unroll
      for (int c = 0; c < 20; ++c){
        vv[c] = S.ppm[b*34 + c] + S.ppm[544 + b*34 + c] + S.bmdL[c];
        mx = fmaxf(mx, vv[c]);
      }
      float sum = 0.f;
#pragma unroll
      for (int c = 0; c < 20; ++c){ vv[c] = __expf(vv[c] - mx); sum += vv[c]; }
      const float inv = 1.f/sum;
#pragma unroll
      for (int c = 0; c < 20; ++c) out[OW_W + bt*20 + c] = vv[c]*inv;
    }
    __syncthreads();

    // ---- publish h slices ----
    if (t < TT && tid < 16){
      u16x8 v = *(const u16x8*)(S.h1b + tid*8);
      st_x4_sc(h1pub + (t&(RD-1))*(BT*HH) + (bg16 + tid)*HH + s*8, v);
    }
    if (t >= 1 && t <= TT && tid >= 16 && tid < 32){
      const int b = tid - 16;
      u16x8 v = *(const u16x8*)(S.h2b + b*8);
      st_x4_sc(h2pub + ((t+RD-1)&(RD-1))*(BT*HH) + (bg16 + b)*HH + s*8, v);
    }
    vmwait0();
    __syncthreads();
    if (tid == 0) st_dword_sc(fl + s, (u32)(t+1));
  }
}

extern "C" void kernel_launch(void* const* d_in, const int* in_sizes, int n_in,
                              void* d_out, int out_size, void* d_ws, size_t ws_size,
                              hipStream_t stream)
{
  const float* strks   = (const float*)d_in[0];
  const float* sentsm  = (const float*)d_in[3];
  const float* onehots = (const float*)d_in[4];
  const float* wprev   = (const float*)d_in[5];
  const float* Wih1 = (const float*)d_in[6];
  const float* Whh1 = (const float*)d_in[7];
  const float* bih1 = (const float*)d_in[8];
  const float* bhh1 = (const float*)d_in[9];
  const float* Wih2 = (const float*)d_in[10];
  const float* Whh2 = (const float*)d_in[11];
  const float* bih2 = (const float*)d_in[12];
  const float* bhh2 = (const float*)d_in[13];
  const float* Wsw  = (const float*)d_in[14];
  const float* bsw  = (const float*)d_in[15];
  const float* Wmdn = (const float*)d_in[16];
  const float* bmdn = (const float*)d_in[17];
  (void)in_sizes; (void)n_in; (void)out_size;

  if (ws_size < (size_t)WS_NEED) return;

  hipMemsetAsync(d_ws, 0, ZERO_BYTES, stream);
  pack_kernel<<<2048, 256, 0, stream>>>(Wih1, Whh1, bih1, bhh1, Wih2, Whh2, bih2, bhh2,
                                        Wsw, bsw, Wmdn, bmdn, onehots, (char*)d_ws);
  rnn_main<<<NBLK, 256, 0, stream>>>(strks, sentsm, wprev, (char*)d_ws, (float*)d_out);
}